// Round 7
// baseline (297.277 us; speedup 1.0000x reference)
//
#include <hip/hip_runtime.h>
#include <hip/hip_bf16.h>
#include <math.h>

#define N_NODES  50000
#define IN_DIM   128
#define HIDDEN   64
#define OUT_DIM  3
#define HEADS1   4
#define E_RAW    400000
#define E_TOT    450000   // raw edges + one self loop per node
#define NEG_SLOPE 0.2f
#define WPREP_BLOCKS 128
#define EB_SC ((E_TOT + 255) / 256)      // 1758 edge blocks
#define MB_GE (N_NODES / 16)             // 3125 gemm row-blocks

typedef __attribute__((ext_vector_type(8))) short bf16x8;
typedef __attribute__((ext_vector_type(4))) float f32x4;

// bf16 bits <-> float helpers (RN pack, shift-based unpack)
static __device__ __forceinline__ float bfu(unsigned short u) {
    return __uint_as_float(((unsigned)u) << 16);
}
static __device__ __forceinline__ unsigned short f2b_bits(float v) {
    __hip_bfloat16 b = __float2bfloat16(v);
    return *reinterpret_cast<unsigned short*>(&b);
}

// ---- edge fetch, robust to int32 vs int64 storage, indices clamped ----
static __device__ __forceinline__ void get_edge(const int* __restrict__ ei, int is64,
                                                int e, int& s, int& d) {
    if (e >= E_RAW) { s = d = e - E_RAW; return; }   // self loop
    if (is64) { s = ei[2 * e]; d = ei[2 * E_RAW + 2 * e]; }
    else      { s = ei[e];     d = ei[E_RAW + e]; }
    s = min(max(s, 0), N_NODES - 1);
    d = min(max(d, 0), N_NODES - 1);
}

// ---- per-BLOCK local int64-layout detection (no flag kernel, no global state).
// Each edge block samples the high words of ITS OWN edges (>=128 real samples per
// block that touches ei). int32 layout -> samples are random node ids, P(all 0)
// ~ (2e-5)^128 = 0. int64 layout -> all high words are 0. Self-loop-only blocks
// never read ei so their (vacuous) verdict is harmless.
static __device__ __forceinline__ int block_is64(const int* __restrict__ ei,
                                                 int e, bool valid, int* nzbuf) {
    bool real = valid && (e < E_RAW);
    int hv = real ? ei[2 * e + 1] : 0;
    if (threadIdx.x == 0) *nzbuf = 0;
    __syncthreads();
    if (__any(hv != 0) && (threadIdx.x & 63) == 0) *nzbuf = 1;
    __syncthreads();
    return (*nzbuf == 0);
}

// ================= fused: weight prep (blocks 0..127) + degree count (rest) =================
__global__ void wprep_count_kernel(const float* __restrict__ W1, __hip_bfloat16* __restrict__ W1T,
                                   const float* __restrict__ W2, __hip_bfloat16* __restrict__ W2T,
                                   const int* __restrict__ ei, int* __restrict__ deg) {
    __shared__ int nz;
    int bid = blockIdx.x;
    if (bid < WPREP_BLOCKS) {
        int i = bid * 256 + threadIdx.x;       // covers 32768 = 256*128
        if (i < 256 * 128) {
            int n = i >> 7, k = i & 127;
            *((unsigned short*)W1T + i) = f2b_bits(W1[k * 256 + n]);
        }
        if (i < 64 * 256) {
            int n = i >> 8, k = i & 255;
            *((unsigned short*)W2T + i) = f2b_bits(W2[k * 64 + n]);
        }
        return;
    }
    int e = (bid - WPREP_BLOCKS) * 256 + threadIdx.x;
    bool valid = e < E_TOT;
    int is64 = block_is64(ei, e, valid, &nz);
    if (!valid) return;
    int s, d;
    get_edge(ei, is64, e, s, d);
    atomicAdd(&deg[d], 1);
}

// ===== FULL prefix scan of deg in ONE small kernel (1 block, 49 chunks, reg carry) =====
__global__ void scan_all_kernel(const int* __restrict__ deg, int* __restrict__ row_ptr,
                                int* __restrict__ cursor) {
    __shared__ int wsum[4];
    const int t = threadIdx.x, wv = t >> 6, ln = t & 63;
    int carry = 0;
    if (t == 0) row_ptr[0] = 0;
    for (int chunk = 0; chunk < 49; ++chunk) {
        int g = chunk * 256 + t;             // int4 group index; 12500 total
        int4 d = (g < 12500) ? ((const int4*)deg)[g] : make_int4(0, 0, 0, 0);
        int p0 = d.x, p1 = p0 + d.y, p2 = p1 + d.z, p3 = p2 + d.w;
        int s = p3;
        #pragma unroll
        for (int off = 1; off < 64; off <<= 1) {
            int u = __shfl_up(s, off, 64);
            if (ln >= off) s += u;
        }
        if (ln == 63) wsum[wv] = s;
        __syncthreads();
        int wbase = carry;
        #pragma unroll
        for (int w = 0; w < 4; w++) wbase += (w < wv) ? wsum[w] : 0;
        int ex = wbase + s - p3;             // exclusive prefix for this thread's 4 elems
        if (g < 12500) {
            int i = g * 4;
            row_ptr[i + 1] = ex + p0; row_ptr[i + 2] = ex + p1;
            row_ptr[i + 3] = ex + p2; row_ptr[i + 4] = ex + p3;
            cursor[i]     = ex;       cursor[i + 1]  = ex + p0;
            cursor[i + 2] = ex + p1;  cursor[i + 3]  = ex + p2;
        }
        carry += wsum[0] + wsum[1] + wsum[2] + wsum[3];
        __syncthreads();
    }
}

// ========== FUSED dispatch: scatter (blocks < EB_SC) + layer-1 MFMA GEMM (rest) ==========
// Independent work co-scheduled (R6-proven): scatter is atomic/latency-bound,
// gemm is MFMA/LDS-bound.
__global__ void __launch_bounds__(256) scatter_gemm_l1_kernel(
        const int* __restrict__ ei,
        int* __restrict__ cursor, int* __restrict__ csr_src,
        const float* __restrict__ x, const __hip_bfloat16* __restrict__ W1T,
        const float* __restrict__ att_s, const float* __restrict__ att_d,
        __hip_bfloat16* __restrict__ h1,
        float* __restrict__ asb4, float* __restrict__ adb4) {
    __shared__ unsigned short As[16][136];
    __shared__ int nz;
    if (blockIdx.x < EB_SC) {
        int e = blockIdx.x * 256 + threadIdx.x;
        bool valid = e < E_TOT;
        int is64 = block_is64(ei, e, valid, &nz);
        if (!valid) return;
        int s, d;
        get_edge(ei, is64, e, s, d);
        int pos = atomicAdd(&cursor[d], 1);
        csr_src[pos] = s;
        return;
    }
    const int tid = threadIdx.x;
    const int wave = tid >> 6, lane = tid & 63;
    const int quad = lane >> 4, m = lane & 15;
    const int row0 = (blockIdx.x - EB_SC) * 16;      // 50000/16 = 3125 exact
    {
        int r = tid >> 4, seg = tid & 15;
        const float* xa = x + (size_t)(row0 + r) * IN_DIM + seg * 8;
        float4 u = *(const float4*)xa;
        float4 v = *(const float4*)(xa + 4);
        ushort4 p0, p1;
        p0.x = f2b_bits(u.x); p0.y = f2b_bits(u.y); p0.z = f2b_bits(u.z); p0.w = f2b_bits(u.w);
        p1.x = f2b_bits(v.x); p1.y = f2b_bits(v.y); p1.z = f2b_bits(v.z); p1.w = f2b_bits(v.w);
        *(ushort4*)&As[r][seg * 8]     = p0;
        *(ushort4*)&As[r][seg * 8 + 4] = p1;
    }
    __syncthreads();
    const int n0w = wave * 64;
    f32x4 acc0 = {0.f, 0.f, 0.f, 0.f}, acc1 = acc0, acc2 = acc0, acc3 = acc0;
    #pragma unroll
    for (int k0 = 0; k0 < IN_DIM; k0 += 32) {
        int kk = k0 + quad * 8;
        bf16x8 a = *(const bf16x8*)&As[m][kk];
        bf16x8 b0 = *(const bf16x8*)(W1T + (size_t)(n0w +  0 + m) * IN_DIM + kk);
        bf16x8 b1 = *(const bf16x8*)(W1T + (size_t)(n0w + 16 + m) * IN_DIM + kk);
        bf16x8 b2 = *(const bf16x8*)(W1T + (size_t)(n0w + 32 + m) * IN_DIM + kk);
        bf16x8 b3 = *(const bf16x8*)(W1T + (size_t)(n0w + 48 + m) * IN_DIM + kk);
        acc0 = __builtin_amdgcn_mfma_f32_16x16x32_bf16(a, b0, acc0, 0, 0, 0);
        acc1 = __builtin_amdgcn_mfma_f32_16x16x32_bf16(a, b1, acc1, 0, 0, 0);
        acc2 = __builtin_amdgcn_mfma_f32_16x16x32_bf16(a, b2, acc2, 0, 0, 0);
        acc3 = __builtin_amdgcn_mfma_f32_16x16x32_bf16(a, b3, acc3, 0, 0, 0);
    }
    float ats0 = att_s[n0w +  0 + m], atd0 = att_d[n0w +  0 + m];
    float ats1 = att_s[n0w + 16 + m], atd1 = att_d[n0w + 16 + m];
    float ats2 = att_s[n0w + 32 + m], atd2 = att_d[n0w + 32 + m];
    float ats3 = att_s[n0w + 48 + m], atd3 = att_d[n0w + 48 + m];
    unsigned short* out = (unsigned short*)h1;
    #pragma unroll
    for (int i = 0; i < 4; i++) {
        int grow = row0 + quad * 4 + i;
        size_t base = (size_t)grow * 256;
        out[base + n0w +  0 + m] = f2b_bits(acc0[i]);
        out[base + n0w + 16 + m] = f2b_bits(acc1[i]);
        out[base + n0w + 32 + m] = f2b_bits(acc2[i]);
        out[base + n0w + 48 + m] = f2b_bits(acc3[i]);
        float ps = acc0[i] * ats0 + acc1[i] * ats1 + acc2[i] * ats2 + acc3[i] * ats3;
        float pd = acc0[i] * atd0 + acc1[i] * atd1 + acc2[i] * atd2 + acc3[i] * atd3;
        #pragma unroll
        for (int off = 1; off < 16; off <<= 1) {
            ps += __shfl_xor(ps, off, 16);
            pd += __shfl_xor(pd, off, 16);
        }
        if (m == 0) {
            asb4[grow * 4 + wave] = ps;
            adb4[grow * 4 + wave] = pd;
        }
    }
}

// ========== gather4 (standalone, R1-proven 48us body): inline softmax+bias+elu ==========
__global__ void __launch_bounds__(256) gat_gather4_kernel(
        const int* __restrict__ row_ptr, const int* __restrict__ csr_src,
        const float* __restrict__ asb4, const float* __restrict__ adb4,
        const __hip_bfloat16* __restrict__ h1, const float* __restrict__ bias,
        __hip_bfloat16* __restrict__ eluagg) {
    int wave = threadIdx.x >> 6;
    int lane = threadIdx.x & 63;
    int n = blockIdx.x * 4 + wave;
    if (n >= N_NODES) return;
    int b = row_ptr[n], e = row_ptr[n + 1];
    const int c    = lane & 31;   // 16B segment within the 512B row
    const int slot = lane >> 5;   // 2 edge slots per wave
    const int head = c >> 3;      // head consumed by this lane's values
    const int ei   = lane >> 2;   // weight phase: edge handled by this lane
    const int hh   = lane & 3;    // weight phase: head handled by this lane
    float adnh = adb4[n * 4 + hh];
    float acc[8];
    #pragma unroll
    for (int i = 0; i < 8; i++) acc[i] = 0.f;
    float l = 0.f;
    for (int c0 = b; c0 < e; c0 += 16) {
        int cnt = min(16, e - c0);
        int s_all = (lane < cnt) ? csr_src[c0 + lane] : 0;
        int sE = __shfl(s_all, ei, 64);
        float w_all = 0.f;
        if (ei < cnt) {
            float v = asb4[sE * 4 + hh] + adnh;
            v = (v > 0.f) ? v : NEG_SLOPE * v;
            w_all = __expf(v);
        }
        #pragma unroll 2
        for (int k = 0; k < cnt; k += 2) {
            int eidx = k + slot;                       // tail: w==0, s==0 -> adds 0
            int s = __shfl(s_all, eidx, 64);
            float w = __shfl(w_all, eidx * 4 + head, 64);
            bf16x8 f = *(const bf16x8*)(h1 + (size_t)s * 256 + c * 8);
            l += w;
            #pragma unroll
            for (int i = 0; i < 8; i++)
                acc[i] += w * bfu((unsigned short)f[i]);
        }
    }
    #pragma unroll
    for (int i = 0; i < 8; i++) acc[i] += __shfl_xor(acc[i], 32, 64);
    l += __shfl_xor(l, 32, 64);
    if (lane < 32) {
        float il = 1.f / (l + 1e-16f);
        float4 b0 = *(const float4*)(bias + c * 8);
        float4 b1 = *(const float4*)(bias + c * 8 + 4);
        float r[8];
        r[0] = acc[0] * il + b0.x; r[1] = acc[1] * il + b0.y;
        r[2] = acc[2] * il + b0.z; r[3] = acc[3] * il + b0.w;
        r[4] = acc[4] * il + b1.x; r[5] = acc[5] * il + b1.y;
        r[6] = acc[6] * il + b1.z; r[7] = acc[7] * il + b1.w;
        bf16x8 st;
        #pragma unroll
        for (int i = 0; i < 8; i++) {
            float v = (r[i] > 0.f) ? r[i] : expm1f(r[i]);
            st[i] = (short)f2b_bits(v);
        }
        *(bf16x8*)(eluagg + (size_t)n * 256 + c * 8) = st;
    }
}

// ========== layer-2 GEMM via MFMA + fused single-head attn scores (R1-proven) ==========
__global__ void __launch_bounds__(256) gemm_l2_mfma_kernel(
        const __hip_bfloat16* __restrict__ eluagg, const __hip_bfloat16* __restrict__ W2T,
        const float* __restrict__ att_s, const float* __restrict__ att_d,
        __hip_bfloat16* __restrict__ h2,
        float* __restrict__ asb, float* __restrict__ adb) {
    __shared__ float sPS[4][16];
    __shared__ float sPD[4][16];
    const int tid = threadIdx.x;
    const int wave = tid >> 6, lane = tid & 63;
    const int quad = lane >> 4, m = lane & 15;
    const int row0 = blockIdx.x * 16;
    const int n0 = wave * 16;
    f32x4 acc = {0.f, 0.f, 0.f, 0.f};
    #pragma unroll
    for (int k0 = 0; k0 < 256; k0 += 32) {
        int kk = k0 + quad * 8;
        bf16x8 a = *(const bf16x8*)(eluagg + (size_t)(row0 + m) * 256 + kk);
        bf16x8 b = *(const bf16x8*)(W2T + (size_t)(n0 + m) * 256 + kk);
        acc = __builtin_amdgcn_mfma_f32_16x16x32_bf16(a, b, acc, 0, 0, 0);
    }
    float ats = att_s[n0 + m], atd = att_d[n0 + m];
    unsigned short* out = (unsigned short*)h2;
    #pragma unroll
    for (int i = 0; i < 4; i++) {
        int grow = row0 + quad * 4 + i;
        out[(size_t)grow * 64 + n0 + m] = f2b_bits(acc[i]);
        float ps = acc[i] * ats;
        float pd = acc[i] * atd;
        #pragma unroll
        for (int off = 1; off < 16; off <<= 1) {
            ps += __shfl_xor(ps, off, 16);
            pd += __shfl_xor(pd, off, 16);
        }
        if (m == 0) {
            sPS[wave][quad * 4 + i] = ps;
            sPD[wave][quad * 4 + i] = pd;
        }
    }
    __syncthreads();
    if (tid < 16) {
        float ps = sPS[0][tid] + sPS[1][tid] + sPS[2][tid] + sPS[3][tid];
        float pd = sPD[0][tid] + sPD[1][tid] + sPD[2][tid] + sPD[3][tid];
        asb[row0 + tid] = ps;
        adb[row0 + tid] = pd;
    }
}

// ========== gather1 + output projection: coalesced preload, 8 edges/iter ==========
__global__ void __launch_bounds__(256) gat_gather1_out_kernel(
        const int* __restrict__ row_ptr, const int* __restrict__ csr_src,
        const float* __restrict__ asb, const float* __restrict__ adb,
        const __hip_bfloat16* __restrict__ h2, const float* __restrict__ bias,
        const float* __restrict__ Wout, const float* __restrict__ bout,
        float* __restrict__ out) {
    int wave = threadIdx.x >> 6;
    int lane = threadIdx.x & 63;
    int n = blockIdx.x * 4 + wave;
    if (n >= N_NODES) return;
    int b = row_ptr[n], e = row_ptr[n + 1];
    const int c    = lane & 7;    // 16B segment within the 128B row
    const int slot = lane >> 3;   // 8 edge slots per wave
    float adn = adb[n];
    float acc[8];
    #pragma unroll
    for (int i = 0; i < 8; i++) acc[i] = 0.f;
    float l = 0.f;
    for (int c0 = b; c0 < e; c0 += 64) {
        int cnt = min(64, e - c0);
        int s_all = (lane < cnt) ? csr_src[c0 + lane] : 0;
        float w_all = 0.f;
        if (lane < cnt) {
            float v = asb[s_all] + adn;
            v = (v > 0.f) ? v : NEG_SLOPE * v;
            w_all = __expf(v);
        }
        #pragma unroll 2
        for (int k = 0; k < cnt; k += 8) {
            int eidx = k + slot;                       // tail: w==0, s==0 -> adds 0
            int s = __shfl(s_all, eidx, 64);
            float w = __shfl(w_all, eidx, 64);
            bf16x8 f = *(const bf16x8*)(h2 + (size_t)s * 64 + c * 8);
            l += w;
            #pragma unroll
            for (int i = 0; i < 8; i++)
                acc[i] += w * bfu((unsigned short)f[i]);
        }
    }
    // reduce across the 8 edge slots (lane bits 3,4,5)
    #pragma unroll
    for (int off = 8; off < 64; off <<= 1) {
        #pragma unroll
        for (int i = 0; i < 8; i++) acc[i] += __shfl_xor(acc[i], off, 64);
        l += __shfl_xor(l, off, 64);
    }
    float il = 1.f / (l + 1e-16f);
    float4 b0 = *(const float4*)(bias + c * 8);
    float4 b1 = *(const float4*)(bias + c * 8 + 4);
    float v[8];
    v[0] = acc[0] * il + b0.x; v[1] = acc[1] * il + b0.y;
    v[2] = acc[2] * il + b0.z; v[3] = acc[3] * il + b0.w;
    v[4] = acc[4] * il + b1.x; v[5] = acc[5] * il + b1.y;
    v[6] = acc[6] * il + b1.z; v[7] = acc[7] * il + b1.w;
    #pragma unroll
    for (int i = 0; i < 8; i++) v[i] = (v[i] > 0.f) ? v[i] : expm1f(v[i]);
    // per-lane partial projection: values (c*8+i) -> Wout[(c*8+i)*3 + k]
    const float* wp = Wout + c * 24;
    float o0 = 0.f, o1 = 0.f, o2 = 0.f;
    #pragma unroll
    for (int i = 0; i < 8; i++) {
        o0 += v[i] * wp[i * 3 + 0];
        o1 += v[i] * wp[i * 3 + 1];
        o2 += v[i] * wp[i * 3 + 2];
    }
    #pragma unroll
    for (int off = 1; off < 8; off <<= 1) {
        o0 += __shfl_xor(o0, off, 64);
        o1 += __shfl_xor(o1, off, 64);
        o2 += __shfl_xor(o2, off, 64);
    }
    if (lane == 0) {
        out[n * OUT_DIM + 0] = o0 + bout[0];
        out[n * OUT_DIM + 1] = o1 + bout[1];
        out[n * OUT_DIM + 2] = o2 + bout[2];
    }
}

extern "C" void kernel_launch(void* const* d_in, const int* in_sizes, int n_in,
                              void* d_out, int out_size, void* d_ws, size_t ws_size,
                              hipStream_t stream) {
    const float* x    = (const float*)d_in[0];
    const int*   ei   = (const int*)d_in[1];
    const float* W1   = (const float*)d_in[2];
    const float* as1  = (const float*)d_in[3];
    const float* ad1  = (const float*)d_in[4];
    const float* b1   = (const float*)d_in[5];
    const float* W2   = (const float*)d_in[6];
    const float* as2  = (const float*)d_in[7];
    const float* ad2  = (const float*)d_in[8];
    const float* b2v  = (const float*)d_in[9];
    const float* Wout = (const float*)d_in[10];
    const float* bout = (const float*)d_in[11];
    float* out = (float*)d_out;

    // ---- workspace layout (~62 MB, proven envelope) ----
    float* ws    = (float*)d_ws;
    float* asb4  = ws + 16;                           // [N,4]
    float* adb4  = asb4 + (size_t)N_NODES * 4;        // [N,4]
    float* asb1  = adb4 + (size_t)N_NODES * 4;        // [N]
    float* adb1  = asb1 + N_NODES;                    // [N]
    __hip_bfloat16* h1     = (__hip_bfloat16*)(adb1 + N_NODES);               // [N,256] bf16
    __hip_bfloat16* eluagg = (__hip_bfloat16*)(h1 + (size_t)N_NODES * 256);   // [N,256] bf16
    __hip_bfloat16* h2     = (__hip_bfloat16*)(eluagg + (size_t)N_NODES * 256); // [N,64] bf16
    __hip_bfloat16* W1T    = (__hip_bfloat16*)(h2 + (size_t)N_NODES * 64);    // [256,128] bf16
    __hip_bfloat16* W2T    = W1T + 256 * 128;                                  // [64,256] bf16
    int* deg     = (int*)(W2T + 64 * 256);            // [N] (16B-aligned)
    int* row_ptr = deg + N_NODES;                     // [N+1] (+pad)
    int* cursor  = row_ptr + N_NODES + 16;            // [N]
    int* csr_src = cursor + N_NODES;                  // [E]

    const int EB = EB_SC;
    const int AB = (N_NODES + 3) / 4;

    // ---- 7-boundary pipeline, all-proven kernel bodies ----
    hipMemsetAsync(deg, 0, (size_t)N_NODES * sizeof(int), stream);
    wprep_count_kernel<<<WPREP_BLOCKS + EB, 256, 0, stream>>>(W1, W1T, W2, W2T, ei, deg);
    scan_all_kernel<<<1, 256, 0, stream>>>(deg, row_ptr, cursor);

    // FUSED: scatter + layer-1 MFMA GEMM (independent, co-scheduled; R6-proven)
    scatter_gemm_l1_kernel<<<EB + MB_GE, 256, 0, stream>>>(ei, cursor, csr_src,
                                                           x, W1T, as1, ad1, h1, asb4, adb4);

    // layer-1 aggregate (standalone R1-proven 48us body)
    gat_gather4_kernel<<<AB, 256, 0, stream>>>(row_ptr, csr_src, asb4, adb4, h1, b1, eluagg);

    // layer-2 GEMM (standalone R1-proven body)
    gemm_l2_mfma_kernel<<<MB_GE, 256, 0, stream>>>(eluagg, W2T, as2, ad2, h2, asb1, adb1);

    // layer-2 aggregate + output projection
    gat_gather1_out_kernel<<<AB, 256, 0, stream>>>(row_ptr, csr_src, asb1, adb1, h2,
                                                   b2v, Wout, bout, out);
}

// Round 8
// 260.738 us; speedup vs baseline: 1.1401x; 1.1401x over previous
//
#include <hip/hip_runtime.h>
#include <hip/hip_bf16.h>
#include <math.h>

#define N_NODES  50000
#define IN_DIM   128
#define HIDDEN   64
#define OUT_DIM  3
#define HEADS1   4
#define E_RAW    400000
#define E_TOT    450000   // raw edges + one self loop per node
#define NEG_SLOPE 0.2f
#define N_CHUNKS 49
#define WPREP_BLOCKS 128
#define EB_SC ((E_TOT + 255) / 256)      // 1758 edge blocks
#define MB_GE (N_NODES / 16)             // 3125 gemm row-blocks

typedef __attribute__((ext_vector_type(8))) short bf16x8;
typedef __attribute__((ext_vector_type(4))) float f32x4;

// bf16 bits <-> float helpers (RN pack, shift-based unpack)
static __device__ __forceinline__ float bfu(unsigned short u) {
    return __uint_as_float(((unsigned)u) << 16);
}
static __device__ __forceinline__ unsigned short f2b_bits(float v) {
    __hip_bfloat16 b = __float2bfloat16(v);
    return *reinterpret_cast<unsigned short*>(&b);
}

// ---- edge fetch, robust to int32 vs int64 storage, indices clamped ----
static __device__ __forceinline__ void get_edge(const int* __restrict__ ei, int is64,
                                                int e, int& s, int& d) {
    if (e >= E_RAW) { s = d = e - E_RAW; return; }   // self loop
    if (is64) { s = ei[2 * e]; d = ei[2 * E_RAW + 2 * e]; }
    else      { s = ei[e];     d = ei[E_RAW + e]; }
    s = min(max(s, 0), N_NODES - 1);
    d = min(max(d, 0), N_NODES - 1);
}

// ---- per-BLOCK local int64-layout detection (R7-proven). Each edge block samples
// the high words of ITS OWN edges; int32 layout -> random node ids, P(all 0 over
// >=128 samples) ~ 0; int64 layout -> all high words 0.
static __device__ __forceinline__ int block_is64(const int* __restrict__ ei,
                                                 int e, bool valid, int* nzbuf) {
    bool real = valid && (e < E_RAW);
    int hv = real ? ei[2 * e + 1] : 0;
    if (threadIdx.x == 0) *nzbuf = 0;
    __syncthreads();
    if (__any(hv != 0) && (threadIdx.x & 63) == 0) *nzbuf = 1;
    __syncthreads();
    return (*nzbuf == 0);
}

// ================= fused: weight prep (blocks 0..127) + degree count (rest) =================
__global__ void wprep_count_kernel(const float* __restrict__ W1, __hip_bfloat16* __restrict__ W1T,
                                   const float* __restrict__ W2, __hip_bfloat16* __restrict__ W2T,
                                   const int* __restrict__ ei, int* __restrict__ deg) {
    __shared__ int nz;
    int bid = blockIdx.x;
    if (bid < WPREP_BLOCKS) {
        int i = bid * 256 + threadIdx.x;       // covers 32768 = 256*128
        if (i < 256 * 128) {
            int n = i >> 7, k = i & 127;
            *((unsigned short*)W1T + i) = f2b_bits(W1[k * 256 + n]);
        }
        if (i < 64 * 256) {
            int n = i >> 8, k = i & 255;
            *((unsigned short*)W2T + i) = f2b_bits(W2[k * 64 + n]);
        }
        return;
    }
    int e = (bid - WPREP_BLOCKS) * 256 + threadIdx.x;
    bool valid = e < E_TOT;
    int is64 = block_is64(ei, e, valid, &nz);
    if (!valid) return;
    int s, d;
    get_edge(ei, is64, e, s, d);
    atomicAdd(&deg[d], 1);
}

// ===== scan in ONE dispatch, no inter-block dependency: block j redundantly sums
// deg[0 .. j*1024) (L2-hot, <=48 int4-iters/thread), then scans its own chunk. =====
__global__ void scan_fused_kernel(const int* __restrict__ deg, int* __restrict__ row_ptr,
                                  int* __restrict__ cursor) {
    __shared__ int wsum[4];
    __shared__ int sbase;
    const int bid = blockIdx.x, t = threadIdx.x, wv = t >> 6, ln = t & 63;
    // (1) base = sum of all degrees before this chunk
    int base = 0;
    const int ng = bid * 256;            // int4 groups before this chunk
    for (int g = t; g < ng; g += 256) {
        int4 d = ((const int4*)deg)[g];
        base += (d.x + d.y) + (d.z + d.w);
    }
    #pragma unroll
    for (int off = 1; off < 64; off <<= 1) base += __shfl_xor(base, off, 64);
    if (ln == 0) wsum[wv] = base;
    __syncthreads();
    if (t == 0) sbase = wsum[0] + wsum[1] + wsum[2] + wsum[3];
    __syncthreads();
    base = sbase;
    // (2) scan own chunk (int4 per thread, 1024 nodes)
    int g = bid * 256 + t;
    int4 d = (g < 12500) ? ((const int4*)deg)[g] : make_int4(0, 0, 0, 0);
    int p0 = d.x, p1 = p0 + d.y, p2 = p1 + d.z, p3 = p2 + d.w;
    int s = p3;
    #pragma unroll
    for (int off = 1; off < 64; off <<= 1) {
        int u = __shfl_up(s, off, 64);
        if (ln >= off) s += u;
    }
    if (ln == 63) wsum[wv] = s;
    __syncthreads();
    int wbase = base;
    #pragma unroll
    for (int w = 0; w < 4; w++) wbase += (w < wv) ? wsum[w] : 0;
    int ex = wbase + s - p3;             // exclusive prefix for this thread's 4 nodes
    if (g < 12500) {
        int i = g * 4;
        row_ptr[i + 1] = ex + p0; row_ptr[i + 2] = ex + p1;
        row_ptr[i + 3] = ex + p2; row_ptr[i + 4] = ex + p3;
        cursor[i]     = ex;       cursor[i + 1]  = ex + p0;
        cursor[i + 2] = ex + p1;  cursor[i + 3]  = ex + p2;
    }
    if (bid == 0 && t == 0) row_ptr[0] = 0;
}

// ========== FUSED dispatch: scatter (blocks < EB_SC) + layer-1 MFMA GEMM (rest) ==========
// h1 C-tile staged in LDS, then stored as full-line bf16x8 (kills 1.7x write amp).
__global__ void __launch_bounds__(256) scatter_gemm_l1_kernel(
        const int* __restrict__ ei,
        int* __restrict__ cursor, int* __restrict__ csr_src,
        const float* __restrict__ x, const __hip_bfloat16* __restrict__ W1T,
        const float* __restrict__ att_s, const float* __restrict__ att_d,
        __hip_bfloat16* __restrict__ h1,
        float* __restrict__ asb4, float* __restrict__ adb4) {
    __shared__ unsigned short As[16][136];
    __shared__ __attribute__((aligned(16))) unsigned short hT[16][264];
    __shared__ int nz;
    if (blockIdx.x < EB_SC) {
        int e = blockIdx.x * 256 + threadIdx.x;
        bool valid = e < E_TOT;
        int is64 = block_is64(ei, e, valid, &nz);
        if (!valid) return;
        int s, d;
        get_edge(ei, is64, e, s, d);
        int pos = atomicAdd(&cursor[d], 1);
        csr_src[pos] = s;
        return;
    }
    const int tid = threadIdx.x;
    const int wave = tid >> 6, lane = tid & 63;
    const int quad = lane >> 4, m = lane & 15;
    const int row0 = (blockIdx.x - EB_SC) * 16;      // 50000/16 = 3125 exact
    {
        int r = tid >> 4, seg = tid & 15;
        const float* xa = x + (size_t)(row0 + r) * IN_DIM + seg * 8;
        float4 u = *(const float4*)xa;
        float4 v = *(const float4*)(xa + 4);
        ushort4 p0, p1;
        p0.x = f2b_bits(u.x); p0.y = f2b_bits(u.y); p0.z = f2b_bits(u.z); p0.w = f2b_bits(u.w);
        p1.x = f2b_bits(v.x); p1.y = f2b_bits(v.y); p1.z = f2b_bits(v.z); p1.w = f2b_bits(v.w);
        *(ushort4*)&As[r][seg * 8]     = p0;
        *(ushort4*)&As[r][seg * 8 + 4] = p1;
    }
    __syncthreads();
    const int n0w = wave * 64;
    f32x4 acc0 = {0.f, 0.f, 0.f, 0.f}, acc1 = acc0, acc2 = acc0, acc3 = acc0;
    #pragma unroll
    for (int k0 = 0; k0 < IN_DIM; k0 += 32) {
        int kk = k0 + quad * 8;
        bf16x8 a = *(const bf16x8*)&As[m][kk];
        bf16x8 b0 = *(const bf16x8*)(W1T + (size_t)(n0w +  0 + m) * IN_DIM + kk);
        bf16x8 b1 = *(const bf16x8*)(W1T + (size_t)(n0w + 16 + m) * IN_DIM + kk);
        bf16x8 b2 = *(const bf16x8*)(W1T + (size_t)(n0w + 32 + m) * IN_DIM + kk);
        bf16x8 b3 = *(const bf16x8*)(W1T + (size_t)(n0w + 48 + m) * IN_DIM + kk);
        acc0 = __builtin_amdgcn_mfma_f32_16x16x32_bf16(a, b0, acc0, 0, 0, 0);
        acc1 = __builtin_amdgcn_mfma_f32_16x16x32_bf16(a, b1, acc1, 0, 0, 0);
        acc2 = __builtin_amdgcn_mfma_f32_16x16x32_bf16(a, b2, acc2, 0, 0, 0);
        acc3 = __builtin_amdgcn_mfma_f32_16x16x32_bf16(a, b3, acc3, 0, 0, 0);
    }
    float ats0 = att_s[n0w +  0 + m], atd0 = att_d[n0w +  0 + m];
    float ats1 = att_s[n0w + 16 + m], atd1 = att_d[n0w + 16 + m];
    float ats2 = att_s[n0w + 32 + m], atd2 = att_d[n0w + 32 + m];
    float ats3 = att_s[n0w + 48 + m], atd3 = att_d[n0w + 48 + m];
    #pragma unroll
    for (int i = 0; i < 4; i++) {
        int r = quad * 4 + i;
        hT[r][n0w +  0 + m] = f2b_bits(acc0[i]);
        hT[r][n0w + 16 + m] = f2b_bits(acc1[i]);
        hT[r][n0w + 32 + m] = f2b_bits(acc2[i]);
        hT[r][n0w + 48 + m] = f2b_bits(acc3[i]);
        float ps = acc0[i] * ats0 + acc1[i] * ats1 + acc2[i] * ats2 + acc3[i] * ats3;
        float pd = acc0[i] * atd0 + acc1[i] * atd1 + acc2[i] * atd2 + acc3[i] * atd3;
        #pragma unroll
        for (int off = 1; off < 16; off <<= 1) {
            ps += __shfl_xor(ps, off, 16);
            pd += __shfl_xor(pd, off, 16);
        }
        if (m == 0) {
            asb4[(row0 + r) * 4 + wave] = ps;
            adb4[(row0 + r) * 4 + wave] = pd;
        }
    }
    __syncthreads();
    {   // vectorized h1 store: 512 x 16B segments, 2 per thread, full rows contiguous
        unsigned short* hrow = (unsigned short*)h1;
        int r0 = tid >> 5, c0 = tid & 31;
        *(bf16x8*)(hrow + (size_t)(row0 + r0) * 256 + c0 * 8) = *(const bf16x8*)&hT[r0][c0 * 8];
        int S = tid + 256;
        int r1 = S >> 5, c1 = S & 31;
        *(bf16x8*)(hrow + (size_t)(row0 + r1) * 256 + c1 * 8) = *(const bf16x8*)&hT[r1][c1 * 8];
    }
}

// ========== FUSED: gather4 (1 node/wave, 16 waves -> LDS) + layer-2 MFMA + l2 scores ==========
// R5-proven 1024-thread version; Stage-B h2 store now LDS-staged + vectorized.
__global__ void __launch_bounds__(1024, 8) gat_gather4_l2_kernel(
        const int* __restrict__ row_ptr, const int* __restrict__ csr_src,
        const float* __restrict__ asb4, const float* __restrict__ adb4,
        const __hip_bfloat16* __restrict__ h1, const float* __restrict__ bias,
        const __hip_bfloat16* __restrict__ W2T,
        const float* __restrict__ att_s, const float* __restrict__ att_d,
        __hip_bfloat16* __restrict__ h2,
        float* __restrict__ asb, float* __restrict__ adb) {
    __shared__ __attribute__((aligned(16))) unsigned short As[16][264];
    __shared__ __attribute__((aligned(16))) unsigned short hT2[16][72];
    __shared__ float sPS[4][16];
    __shared__ float sPD[4][16];
    const int tid = threadIdx.x;
    const int wave = tid >> 6, lane = tid & 63;
    const int row0 = blockIdx.x * 16;
    const int c    = lane & 31;   // 16B segment within the 512B row
    const int slot = lane >> 5;   // 2 edge slots per wave
    const int head = c >> 3;      // head consumed by this lane's values
    const int eidx0 = lane >> 2;  // weight phase: edge handled by this lane
    const int hh   = lane & 3;    // weight phase: head handled by this lane

    // ---- Stage A: each wave gathers its own node (R1-proven body) ----
    {
        const int n = row0 + wave;
        int b = row_ptr[n], e = row_ptr[n + 1];
        float adnh = adb4[n * 4 + hh];
        float acc[8];
        #pragma unroll
        for (int i = 0; i < 8; i++) acc[i] = 0.f;
        float l = 0.f;
        for (int c0 = b; c0 < e; c0 += 16) {
            int cnt = min(16, e - c0);
            int s_all = (lane < cnt) ? csr_src[c0 + lane] : 0;
            int sE = __shfl(s_all, eidx0, 64);
            float w_all = 0.f;
            if (eidx0 < cnt) {
                float v = asb4[sE * 4 + hh] + adnh;
                v = (v > 0.f) ? v : NEG_SLOPE * v;
                w_all = __expf(v);
            }
            #pragma unroll 2
            for (int k = 0; k < cnt; k += 2) {
                int eidx = k + slot;                   // tail: w==0, s==0 -> adds 0
                int s = __shfl(s_all, eidx, 64);
                float w = __shfl(w_all, eidx * 4 + head, 64);
                bf16x8 f = *(const bf16x8*)(h1 + (size_t)s * 256 + c * 8);
                l += w;
                #pragma unroll
                for (int i = 0; i < 8; i++)
                    acc[i] += w * bfu((unsigned short)f[i]);
            }
        }
        #pragma unroll
        for (int i = 0; i < 8; i++) acc[i] += __shfl_xor(acc[i], 32, 64);
        l += __shfl_xor(l, 32, 64);
        if (lane < 32) {
            float il = 1.f / (l + 1e-16f);
            float4 b0 = *(const float4*)(bias + c * 8);
            float4 b1 = *(const float4*)(bias + c * 8 + 4);
            float r[8];
            r[0] = acc[0] * il + b0.x; r[1] = acc[1] * il + b0.y;
            r[2] = acc[2] * il + b0.z; r[3] = acc[3] * il + b0.w;
            r[4] = acc[4] * il + b1.x; r[5] = acc[5] * il + b1.y;
            r[6] = acc[6] * il + b1.z; r[7] = acc[7] * il + b1.w;
            bf16x8 st;
            #pragma unroll
            for (int i = 0; i < 8; i++) {
                float v = (r[i] > 0.f) ? r[i] : expm1f(r[i]);
                st[i] = (short)f2b_bits(v);
            }
            *(bf16x8*)&As[wave][c * 8] = st;
        }
    }
    __syncthreads();

    // ---- Stage B: layer-2 MFMA from LDS + fused scores (waves 0-3); C -> LDS ----
    if (wave < 4) {
        const int quad = lane >> 4, m = lane & 15;
        const int n0 = wave * 16;
        f32x4 acc = {0.f, 0.f, 0.f, 0.f};
        #pragma unroll
        for (int k0 = 0; k0 < 256; k0 += 32) {
            int kk = k0 + quad * 8;
            bf16x8 a = *(const bf16x8*)&As[m][kk];
            bf16x8 bfr = *(const bf16x8*)(W2T + (size_t)(n0 + m) * 256 + kk);
            acc = __builtin_amdgcn_mfma_f32_16x16x32_bf16(a, bfr, acc, 0, 0, 0);
        }
        float ats = att_s[n0 + m], atd = att_d[n0 + m];
        #pragma unroll
        for (int i = 0; i < 4; i++) {
            int r = quad * 4 + i;
            hT2[r][n0 + m] = f2b_bits(acc[i]);
            float ps = acc[i] * ats;
            float pd = acc[i] * atd;
            #pragma unroll
            for (int off = 1; off < 16; off <<= 1) {
                ps += __shfl_xor(ps, off, 16);
                pd += __shfl_xor(pd, off, 16);
            }
            if (m == 0) {
                sPS[wave][r] = ps;
                sPD[wave][r] = pd;
            }
        }
    }
    __syncthreads();
    if (tid < 128) {   // vectorized h2 store: 128 x 16B segments (full 128B rows)
        int r = tid >> 3, cs = tid & 7;
        *(bf16x8*)((unsigned short*)h2 + (size_t)(row0 + r) * 64 + cs * 8) =
            *(const bf16x8*)&hT2[r][cs * 8];
    }
    if (tid < 16) {
        float ps = sPS[0][tid] + sPS[1][tid] + sPS[2][tid] + sPS[3][tid];
        float pd = sPD[0][tid] + sPD[1][tid] + sPD[2][tid] + sPD[3][tid];
        asb[row0 + tid] = ps;
        adb[row0 + tid] = pd;
    }
}

// ========== gather1 + output projection: coalesced preload, 8 edges/iter ==========
__global__ void __launch_bounds__(256) gat_gather1_out_kernel(
        const int* __restrict__ row_ptr, const int* __restrict__ csr_src,
        const float* __restrict__ asb, const float* __restrict__ adb,
        const __hip_bfloat16* __restrict__ h2, const float* __restrict__ bias,
        const float* __restrict__ Wout, const float* __restrict__ bout,
        float* __restrict__ out) {
    int wave = threadIdx.x >> 6;
    int lane = threadIdx.x & 63;
    int n = blockIdx.x * 4 + wave;
    if (n >= N_NODES) return;
    int b = row_ptr[n], e = row_ptr[n + 1];
    const int c    = lane & 7;    // 16B segment within the 128B row
    const int slot = lane >> 3;   // 8 edge slots per wave
    float adn = adb[n];
    float acc[8];
    #pragma unroll
    for (int i = 0; i < 8; i++) acc[i] = 0.f;
    float l = 0.f;
    for (int c0 = b; c0 < e; c0 += 64) {
        int cnt = min(64, e - c0);
        int s_all = (lane < cnt) ? csr_src[c0 + lane] : 0;
        float w_all = 0.f;
        if (lane < cnt) {
            float v = asb[s_all] + adn;
            v = (v > 0.f) ? v : NEG_SLOPE * v;
            w_all = __expf(v);
        }
        #pragma unroll 2
        for (int k = 0; k < cnt; k += 8) {
            int eidx = k + slot;                       // tail: w==0, s==0 -> adds 0
            int s = __shfl(s_all, eidx, 64);
            float w = __shfl(w_all, eidx, 64);
            bf16x8 f = *(const bf16x8*)(h2 + (size_t)s * 64 + c * 8);
            l += w;
            #pragma unroll
            for (int i = 0; i < 8; i++)
                acc[i] += w * bfu((unsigned short)f[i]);
        }
    }
    // reduce across the 8 edge slots (lane bits 3,4,5)
    #pragma unroll
    for (int off = 8; off < 64; off <<= 1) {
        #pragma unroll
        for (int i = 0; i < 8; i++) acc[i] += __shfl_xor(acc[i], off, 64);
        l += __shfl_xor(l, off, 64);
    }
    float il = 1.f / (l + 1e-16f);
    float4 b0 = *(const float4*)(bias + c * 8);
    float4 b1 = *(const float4*)(bias + c * 8 + 4);
    float v[8];
    v[0] = acc[0] * il + b0.x; v[1] = acc[1] * il + b0.y;
    v[2] = acc[2] * il + b0.z; v[3] = acc[3] * il + b0.w;
    v[4] = acc[4] * il + b1.x; v[5] = acc[5] * il + b1.y;
    v[6] = acc[6] * il + b1.z; v[7] = acc[7] * il + b1.w;
    #pragma unroll
    for (int i = 0; i < 8; i++) v[i] = (v[i] > 0.f) ? v[i] : expm1f(v[i]);
    // per-lane partial projection: values (c*8+i) -> Wout[(c*8+i)*3 + k]
    const float* wp = Wout + c * 24;
    float o0 = 0.f, o1 = 0.f, o2 = 0.f;
    #pragma unroll
    for (int i = 0; i < 8; i++) {
        o0 += v[i] * wp[i * 3 + 0];
        o1 += v[i] * wp[i * 3 + 1];
        o2 += v[i] * wp[i * 3 + 2];
    }
    #pragma unroll
    for (int off = 1; off < 8; off <<= 1) {
        o0 += __shfl_xor(o0, off, 64);
        o1 += __shfl_xor(o1, off, 64);
        o2 += __shfl_xor(o2, off, 64);
    }
    if (lane == 0) {
        out[n * OUT_DIM + 0] = o0 + bout[0];
        out[n * OUT_DIM + 1] = o1 + bout[1];
        out[n * OUT_DIM + 2] = o2 + bout[2];
    }
}

extern "C" void kernel_launch(void* const* d_in, const int* in_sizes, int n_in,
                              void* d_out, int out_size, void* d_ws, size_t ws_size,
                              hipStream_t stream) {
    const float* x    = (const float*)d_in[0];
    const int*   ei   = (const int*)d_in[1];
    const float* W1   = (const float*)d_in[2];
    const float* as1  = (const float*)d_in[3];
    const float* ad1  = (const float*)d_in[4];
    const float* b1   = (const float*)d_in[5];
    const float* W2   = (const float*)d_in[6];
    const float* as2  = (const float*)d_in[7];
    const float* ad2  = (const float*)d_in[8];
    const float* b2v  = (const float*)d_in[9];
    const float* Wout = (const float*)d_in[10];
    const float* bout = (const float*)d_in[11];
    float* out = (float*)d_out;

    // ---- workspace layout (~37 MB; eluagg eliminated) ----
    float* ws    = (float*)d_ws;
    float* asb4  = ws + 16;                           // [N,4]
    float* adb4  = asb4 + (size_t)N_NODES * 4;        // [N,4]
    float* asb1  = adb4 + (size_t)N_NODES * 4;        // [N]
    float* adb1  = asb1 + N_NODES;                    // [N]
    __hip_bfloat16* h1     = (__hip_bfloat16*)(adb1 + N_NODES);               // [N,256] bf16
    __hip_bfloat16* h2     = (__hip_bfloat16*)(h1 + (size_t)N_NODES * 256);   // [N,64] bf16
    __hip_bfloat16* W1T    = (__hip_bfloat16*)(h2 + (size_t)N_NODES * 64);    // [256,128] bf16
    __hip_bfloat16* W2T    = W1T + 256 * 128;                                  // [64,256] bf16
    int* deg     = (int*)(W2T + 64 * 256);            // [N] (16B-aligned)
    int* row_ptr = deg + N_NODES;                     // [N+1] (+pad)
    int* cursor  = row_ptr + N_NODES + 16;            // [N]
    int* csr_src = cursor + N_NODES;                  // [E]

    const int EB = EB_SC;
    const int AB = (N_NODES + 3) / 4;

    // ---- 6-kernel pipeline (+1 memset) ----
    hipMemsetAsync(deg, 0, (size_t)N_NODES * sizeof(int), stream);
    wprep_count_kernel<<<WPREP_BLOCKS + EB, 256, 0, stream>>>(W1, W1T, W2, W2T, ei, deg);
    scan_fused_kernel<<<N_CHUNKS, 256, 0, stream>>>(deg, row_ptr, cursor);

    // FUSED: scatter + layer-1 MFMA GEMM (vectorized h1 store)
    scatter_gemm_l1_kernel<<<EB + MB_GE, 256, 0, stream>>>(ei, cursor, csr_src,
                                                           x, W1T, as1, ad1, h1, asb4, adb4);

    // FUSED: gather4 softmax/bias/elu (LDS) + layer-2 MFMA + l2 scores (vectorized h2 store)
    gat_gather4_l2_kernel<<<MB_GE, 1024, 0, stream>>>(row_ptr, csr_src, asb4, adb4, h1, b1,
                                                      W2T, as2, ad2, h2, asb1, adb1);

    // layer-2 aggregate + output projection
    gat_gather1_out_kernel<<<AB, 256, 0, stream>>>(row_ptr, csr_src, asb1, adb1, h2,
                                                   b2v, Wout, bout, out);
}